// Round 8
// baseline (631.172 us; speedup 1.0000x reference)
//
#include <hip/hip_runtime.h>
#include <math.h>

#define NN 100000
#define NE 1600000
#define INF 128
#define HID 256
#define SCAN_BLK 256
#define NSCAN ((NN + SCAN_BLK - 1) / SCAN_BLK)   // 391
#define FGRP 8                    // node-space partitions
#define FRNG (NN / FGRP)          // 12500 nodes per range
#define NCOPY 16                  // edge-stream chunks = histogram copies
#define CHUNK (NE / NCOPY)        // 100000 edges per chunk

typedef short bf16x8 __attribute__((ext_vector_type(8)));
typedef float f32x4 __attribute__((ext_vector_type(4)));

__device__ __forceinline__ unsigned int f2bf(float f) {
    unsigned int u = __float_as_uint(f);
    u = u + 0x7FFFu + ((u >> 16) & 1u);   // RNE
    return u >> 16;
}

// ---- privatized degree histograms: ZERO global atomics ----
// block (g = blockIdx&7, b = blockIdx>>3): LDS hists over node range
// [g*FRNG,(g+1)*FRNG) for edge chunk [b*CHUNK,(b+1)*CHUNK); flush = plain
// coalesced stores to hist_out[b][·], hist_in[b][·].
__global__ void k_hist(const int* __restrict__ src, const int* __restrict__ dst,
                       int* __restrict__ hist_out, int* __restrict__ hist_in) {
    __shared__ int ho[FRNG];
    __shared__ int hin[FRNG];
    const int g = blockIdx.x & (FGRP - 1);
    const int b = blockIdx.x >> 3;
    const int lo = g * FRNG;
    for (int i = threadIdx.x; i < FRNG; i += 256) { ho[i] = 0; hin[i] = 0; }
    __syncthreads();
    const int e0 = b * CHUNK;
    for (int k = threadIdx.x; k < CHUNK; k += 256) {
        int e = e0 + k;
        int s = src[e] - lo;
        if ((unsigned)s < FRNG) atomicAdd(&ho[s], 1);
        int d = dst[e] - lo;
        if ((unsigned)d < FRNG) atomicAdd(&hin[d], 1);
    }
    __syncthreads();
    int* po = hist_out + (size_t)b * NN + lo;
    int* pi = hist_in  + (size_t)b * NN + lo;
    for (int i = threadIdx.x; i < FRNG; i += 256) { po[i] = ho[i]; pi[i] = hin[i]; }
}

// ---- reduce 16 copies -> norms + deg_in (scan input) ----
__global__ void k_norms2(const int* __restrict__ hist_out, const int* __restrict__ hist_in,
                         float* __restrict__ nrm_out, float* __restrict__ nrm_in,
                         int* __restrict__ deg_in) {
    int v = blockIdx.x * blockDim.x + threadIdx.x;
    if (v < NN) {
        int so = 0, si = 0;
        #pragma unroll
        for (int b = 0; b < NCOPY; ++b) {
            so += hist_out[(size_t)b * NN + v];
            si += hist_in[(size_t)b * NN + v];
        }
        nrm_out[v] = rsqrtf(fmaxf((float)so, 1.0f));
        nrm_in[v]  = rsqrtf(fmaxf((float)si, 1.0f));
        deg_in[v]  = si;
    }
}

// ---- xs = bf16(x * nrm_out[row]), packed 2/uint ----
__global__ void k_xconv(const float* __restrict__ x, const float* __restrict__ nrm_out,
                        unsigned int* __restrict__ xs) {
    int i = blockIdx.x * blockDim.x + threadIdx.x;
    if (i >= NN * (INF / 2)) return;
    int row = i >> 6;
    float n = nrm_out[row];
    float2 v = *reinterpret_cast<const float2*>(x + (size_t)i * 2);
    xs[i] = f2bf(v.x * n) | (f2bf(v.y * n) << 16);
}

// ---- W1 -> fragment-linear bf16 buffer + (b1,W2) pair table ----
__global__ void k_wfrag(const float* __restrict__ W1, const float* __restrict__ b1,
                        const float* __restrict__ W2, unsigned short* __restrict__ fragW,
                        float2* __restrict__ bw) {
    int idx = blockIdx.x * blockDim.x + threadIdx.x;
    if (idx < 4096) {
        int l = idx & 63, ks = (idx >> 6) & 3, nt = idx >> 8;
        int kbase = ks * 32 + ((l >> 4) << 3);
        int col = nt * 16 + (l & 15);
        bf16x8 r;
        #pragma unroll
        for (int i = 0; i < 8; ++i)
            r[i] = (short)f2bf(W1[(size_t)(kbase + i) * HID + col]);
        *reinterpret_cast<bf16x8*>(fragW + (size_t)idx * 8) = r;
    } else if (idx < 4096 + HID) {
        int n = idx - 4096;
        bw[n] = make_float2(b1[n], W2[n]);
    }
}

// ---- scan phase 1: per-block sums of deg_in ----
__global__ void k_scan1(const int* __restrict__ deg_in, int* __restrict__ partial) {
    __shared__ int sh[SCAN_BLK];
    int i = blockIdx.x * SCAN_BLK + threadIdx.x;
    int v = (i < NN) ? deg_in[i] : 0;
    sh[threadIdx.x] = v;
    __syncthreads();
    for (int off = SCAN_BLK / 2; off > 0; off >>= 1) {
        if (threadIdx.x < off) sh[threadIdx.x] += sh[threadIdx.x + off];
        __syncthreads();
    }
    if (threadIdx.x == 0) partial[blockIdx.x] = sh[0];
}

// ---- scan phase 2: wave-parallel exclusive scan of 391 partials ----
__global__ void k_scan2(int* __restrict__ partial) {
    int lane = threadIdx.x;
    int carry = 0;
    for (int c = 0; c < NSCAN; c += 64) {
        int idx = c + lane;
        int v = (idx < NSCAN) ? partial[idx] : 0;
        int s = v;
        #pragma unroll
        for (int off = 1; off < 64; off <<= 1) {
            int t = __shfl_up(s, off, 64);
            if (lane >= off) s += t;
        }
        if (idx < NSCAN) partial[idx] = s - v + carry;
        carry += __shfl(s, 63, 64);
    }
}

// ---- scan phase 3: offsets ----
__global__ void k_scan3(const int* __restrict__ deg_in, const int* __restrict__ partial,
                        int* __restrict__ offsets) {
    __shared__ int sh[SCAN_BLK];
    int i = blockIdx.x * SCAN_BLK + threadIdx.x;
    int v = (i < NN) ? deg_in[i] : 0;
    sh[threadIdx.x] = v;
    __syncthreads();
    for (int off = 1; off < SCAN_BLK; off <<= 1) {
        int t = (threadIdx.x >= off) ? sh[threadIdx.x - off] : 0;
        __syncthreads();
        sh[threadIdx.x] += t;
        __syncthreads();
    }
    int ex = sh[threadIdx.x] - v + partial[blockIdx.x];
    if (i < NN) offsets[i] = ex;
    if (i == 0) offsets[NN] = NE;
}

// ---- per-copy cursor bases: cbase[b][v] = offsets[v] + sum_{b'<b} hist_in[b'][v] ----
__global__ void k_cbase(const int* __restrict__ offsets, const int* __restrict__ hist_in,
                        int* __restrict__ cbase) {
    int v = blockIdx.x * blockDim.x + threadIdx.x;
    if (v < NN) {
        int run = offsets[v];
        #pragma unroll
        for (int b = 0; b < NCOPY; ++b) {
            cbase[(size_t)b * NN + v] = run;
            run += hist_in[(size_t)b * NN + v];
        }
    }
}

// ---- CSR fill with LDS cursors: ZERO global atomics ----
// block (g,b) scans chunk b (same chunking as k_hist => slot counts match
// hist_in[b] exactly); cursor slice seeded from cbase[b], ds_atomic_add.
__global__ void k_fill2(const int* __restrict__ src, const int* __restrict__ dst,
                        const int* __restrict__ cbase, int* __restrict__ csr_src) {
    __shared__ int cur[FRNG];
    const int g = blockIdx.x & (FGRP - 1);
    const int b = blockIdx.x >> 3;
    const int lo = g * FRNG;
    const int* cb = cbase + (size_t)b * NN + lo;
    for (int i = threadIdx.x; i < FRNG; i += 256) cur[i] = cb[i];
    __syncthreads();
    const int e0 = b * CHUNK;
    for (int k = threadIdx.x; k < CHUNK; k += 256) {
        int e = e0 + k;
        int d = dst[e] - lo;
        if ((unsigned)d < FRNG) {
            int p = atomicAdd(&cur[d], 1);
            csr_src[p] = src[e];
        }
    }
}

// ---- gather: aggb[v] = bf16( nrm_in[v] * sum xs[src] ), one wave per row ----
__global__ void k_gather(const unsigned int* __restrict__ xs, const int* __restrict__ offsets,
                         const int* __restrict__ csr_src, const float* __restrict__ nrm_in,
                         unsigned int* __restrict__ aggb) {
    int row = blockIdx.x * 4 + (threadIdx.x >> 6);
    if (row >= NN) return;
    int lane = threadIdx.x & 63;
    int beg = offsets[row], end = offsets[row + 1];
    float a0 = 0.f, a1 = 0.f, b0 = 0.f, b1 = 0.f;
    int j = beg;
    for (; j + 1 < end; j += 2) {
        unsigned int p0 = xs[(size_t)csr_src[j] * 64 + lane];
        unsigned int p1 = xs[(size_t)csr_src[j + 1] * 64 + lane];
        a0 += __uint_as_float(p0 << 16);
        a1 += __uint_as_float(p0 & 0xFFFF0000u);
        b0 += __uint_as_float(p1 << 16);
        b1 += __uint_as_float(p1 & 0xFFFF0000u);
    }
    if (j < end) {
        unsigned int p0 = xs[(size_t)csr_src[j] * 64 + lane];
        a0 += __uint_as_float(p0 << 16);
        a1 += __uint_as_float(p0 & 0xFFFF0000u);
    }
    float ni = nrm_in[row];
    float lo = (a0 + b0) * ni, hi = (a1 + b1) * ni;
    aggb[(size_t)row * 64 + lane] = f2bf(lo) | (f2bf(hi) << 16);
}

// ---- MFMA GEMM (no LDS) + relu + W2-dot + shfl-reduce -> z ----
__launch_bounds__(256)
__global__ void k_gemm(const unsigned short* __restrict__ aggb,
                       const unsigned short* __restrict__ fragW,
                       const float2* __restrict__ bw, const float* __restrict__ nrm_out,
                       float* __restrict__ z) {
    const int l = threadIdx.x & 63;
    const int w = threadIdx.x >> 6;
    const int r0 = blockIdx.x * 64 + w * 16;
    const int n15 = l & 15;
    const int hi = l >> 4;
    const int arow = r0 + n15;

    bf16x8 a[4];
    if (arow < NN) {
        #pragma unroll
        for (int ks = 0; ks < 4; ++ks)
            a[ks] = *reinterpret_cast<const bf16x8*>(aggb + (size_t)arow * INF + ks * 32 + (hi << 3));
    } else {
        #pragma unroll
        for (int ks = 0; ks < 4; ++ks) a[ks] = (bf16x8){0, 0, 0, 0, 0, 0, 0, 0};
    }

    float pacc[4] = {0.f, 0.f, 0.f, 0.f};
    #pragma unroll
    for (int nt = 0; nt < 16; ++nt) {
        f32x4 acc = {0.f, 0.f, 0.f, 0.f};
        #pragma unroll
        for (int ks = 0; ks < 4; ++ks) {
            bf16x8 b = *reinterpret_cast<const bf16x8*>(fragW + (size_t)(((nt * 4 + ks) * 64 + l) << 3));
            acc = __builtin_amdgcn_mfma_f32_16x16x32_bf16(a[ks], b, acc, 0, 0, 0);
        }
        float2 c = bw[nt * 16 + n15];
        #pragma unroll
        for (int g = 0; g < 4; ++g)
            pacc[g] += fmaxf(acc[g] + c.x, 0.f) * c.y;
    }
    #pragma unroll
    for (int off = 1; off < 16; off <<= 1) {
        #pragma unroll
        for (int g = 0; g < 4; ++g) pacc[g] += __shfl_xor(pacc[g], off, 64);
    }
    if (n15 == 0) {
        #pragma unroll
        for (int g = 0; g < 4; ++g) {
            int gr = r0 + (hi << 2) + g;
            if (gr < NN) z[gr] = nrm_out[gr] * pacc[g];
        }
    }
}

// ---- layer-2 gather + sigmoid: 16 lanes per node, shfl reduce ----
__global__ void k_out(const float* __restrict__ z, const int* __restrict__ offsets,
                      const int* __restrict__ csr_src, const float* __restrict__ nrm_in,
                      const float* __restrict__ b2, float* __restrict__ out) {
    int v = blockIdx.x * 16 + (threadIdx.x >> 4);
    if (v >= NN) return;
    int li = threadIdx.x & 15;
    int beg = offsets[v], end = offsets[v + 1];
    float s = 0.f;
    for (int j = beg + li; j < end; j += 16) s += z[csr_src[j]];
    #pragma unroll
    for (int off = 1; off < 16; off <<= 1) s += __shfl_xor(s, off, 64);
    if (li == 0) {
        float val = s * nrm_in[v] + b2[0];
        out[v] = 1.0f / (1.0f + expf(-val));
    }
}

extern "C" void kernel_launch(void* const* d_in, const int* in_sizes, int n_in,
                              void* d_out, int out_size, void* d_ws, size_t ws_size,
                              hipStream_t stream) {
    const float* x   = (const float*)d_in[0];
    const int*   src = (const int*)d_in[1];
    const int*   dst = (const int*)d_in[2];
    const float* W1  = (const float*)d_in[3];
    const float* b1  = (const float*)d_in[4];
    const float* W2  = (const float*)d_in[5];
    const float* b2  = (const float*)d_in[6];
    float* out = (float*)d_out;

    // workspace layout; hist/cbase alias the aggb region (dead until k_gather)
    int*   deg_in  = (int*)d_ws;                     // NN
    int*   offsets = deg_in + NN;                    // NN+1
    int*   partial = offsets + NN + 1;               // NSCAN
    int*   csr_src = partial + NSCAN;                // NE
    float* nrm_out = (float*)(csr_src + NE);         // NN
    float* nrm_in  = nrm_out + NN;                   // NN
    float* z       = nrm_in + NN;                    // NN
    float2* bw     = (float2*)(z + NN);              // HID
    unsigned int* xs   = (unsigned int*)(bw + HID);  // NN*64  (25.6 MB)
    unsigned int* aggb = xs + (size_t)NN * 64;       // NN*64  (25.6 MB)
    unsigned short* fragW = (unsigned short*)(aggb + (size_t)NN * 64);  // 64 KB
    int* hist_out = (int*)aggb;                      // NCOPY*NN (6.4 MB)   aliases aggb
    int* hist_in  = hist_out + (size_t)NCOPY * NN;   // NCOPY*NN (6.4 MB)
    int* cbase    = hist_in + (size_t)NCOPY * NN;    // NCOPY*NN (6.4 MB)

    k_wfrag<<<17, 256, 0, stream>>>(W1, b1, W2, fragW, bw);
    k_hist<<<FGRP * NCOPY, 256, 0, stream>>>(src, dst, hist_out, hist_in);
    k_norms2<<<(NN + 255) / 256, 256, 0, stream>>>(hist_out, hist_in, nrm_out, nrm_in, deg_in);
    k_xconv<<<(NN * 64 + 255) / 256, 256, 0, stream>>>(x, nrm_out, xs);
    k_scan1<<<NSCAN, SCAN_BLK, 0, stream>>>(deg_in, partial);
    k_scan2<<<1, 64, 0, stream>>>(partial);
    k_scan3<<<NSCAN, SCAN_BLK, 0, stream>>>(deg_in, partial, offsets);
    k_cbase<<<(NN + 255) / 256, 256, 0, stream>>>(offsets, hist_in, cbase);
    k_fill2<<<FGRP * NCOPY, 256, 0, stream>>>(src, dst, cbase, csr_src);
    k_gather<<<NN / 4, 256, 0, stream>>>(xs, offsets, csr_src, nrm_in, aggb);
    k_gemm<<<(NN + 63) / 64, 256, 0, stream>>>((const unsigned short*)aggb, fragW, bw, nrm_out, z);
    k_out<<<(NN + 15) / 16, 256, 0, stream>>>(z, offsets, csr_src, nrm_in, b2, out);
}

// Round 9
// 225.570 us; speedup vs baseline: 2.7981x; 2.7981x over previous
//
#include <hip/hip_runtime.h>
#include <math.h>

#define NN 100000
#define NE 1600000
#define INF 128
#define HID 256
#define SCAN_BLK 256
#define NSCAN ((NN + SCAN_BLK - 1) / SCAN_BLK)   // 391
#define FGRP 8                    // node-space partitions
#define FRNG (NN / FGRP)          // 12500 nodes per range
#define NC 32                     // edge-stream chunks = histogram copies
#define CHUNK (NE / NC)           // 50000 edges per chunk

typedef short bf16x8 __attribute__((ext_vector_type(8)));
typedef float f32x4 __attribute__((ext_vector_type(4)));

__device__ __forceinline__ unsigned int f2bf(float f) {
    unsigned int u = __float_as_uint(f);
    u = u + 0x7FFFu + ((u >> 16) & 1u);   // RNE
    return u >> 16;
}

// ---- privatized degree histograms, type-split for occupancy ----
// block (type = bid&1, g = (bid>>1)&7, c = bid>>4): LDS hist (50 KB) over
// node range [g*FRNG,(g+1)*FRNG) of src (type=0) or dst (type=1) for chunk c.
// 1024 thr, int4 loads; flush = plain coalesced stores. Zero global atomics.
__launch_bounds__(1024)
__global__ void k_hist(const int* __restrict__ src, const int* __restrict__ dst,
                       int* __restrict__ hist_out, int* __restrict__ hist_in) {
    __shared__ int h[FRNG];
    const int type = blockIdx.x & 1;
    const int g = (blockIdx.x >> 1) & (FGRP - 1);
    const int c = blockIdx.x >> 4;
    const int lo = g * FRNG;
    for (int i = threadIdx.x; i < FRNG; i += 1024) h[i] = 0;
    __syncthreads();
    const int4* a4 = reinterpret_cast<const int4*>((type ? dst : src) + c * CHUNK);
    for (int k = threadIdx.x; k < CHUNK / 4; k += 1024) {
        int4 v = a4[k];
        int i0 = v.x - lo, i1 = v.y - lo, i2 = v.z - lo, i3 = v.w - lo;
        if ((unsigned)i0 < FRNG) atomicAdd(&h[i0], 1);
        if ((unsigned)i1 < FRNG) atomicAdd(&h[i1], 1);
        if ((unsigned)i2 < FRNG) atomicAdd(&h[i2], 1);
        if ((unsigned)i3 < FRNG) atomicAdd(&h[i3], 1);
    }
    __syncthreads();
    int* out = (type ? hist_in : hist_out) + (size_t)c * NN + lo;
    for (int i = threadIdx.x; i < FRNG; i += 1024) out[i] = h[i];
}

// ---- reduce 32 copies -> norms + deg_in (scan input) ----
__global__ void k_norms2(const int* __restrict__ hist_out, const int* __restrict__ hist_in,
                         float* __restrict__ nrm_out, float* __restrict__ nrm_in,
                         int* __restrict__ deg_in) {
    int v = blockIdx.x * blockDim.x + threadIdx.x;
    if (v < NN) {
        int so = 0, si = 0;
        #pragma unroll
        for (int b = 0; b < NC; ++b) {
            so += hist_out[(size_t)b * NN + v];
            si += hist_in[(size_t)b * NN + v];
        }
        nrm_out[v] = rsqrtf(fmaxf((float)so, 1.0f));
        nrm_in[v]  = rsqrtf(fmaxf((float)si, 1.0f));
        deg_in[v]  = si;
    }
}

// ---- xs = bf16(x * nrm_out[row]), packed 2/uint ----
__global__ void k_xconv(const float* __restrict__ x, const float* __restrict__ nrm_out,
                        unsigned int* __restrict__ xs) {
    int i = blockIdx.x * blockDim.x + threadIdx.x;
    if (i >= NN * (INF / 2)) return;
    int row = i >> 6;
    float n = nrm_out[row];
    float2 v = *reinterpret_cast<const float2*>(x + (size_t)i * 2);
    xs[i] = f2bf(v.x * n) | (f2bf(v.y * n) << 16);
}

// ---- W1 -> fragment-linear bf16 buffer + (b1,W2) pair table ----
__global__ void k_wfrag(const float* __restrict__ W1, const float* __restrict__ b1,
                        const float* __restrict__ W2, unsigned short* __restrict__ fragW,
                        float2* __restrict__ bw) {
    int idx = blockIdx.x * blockDim.x + threadIdx.x;
    if (idx < 4096) {
        int l = idx & 63, ks = (idx >> 6) & 3, nt = idx >> 8;
        int kbase = ks * 32 + ((l >> 4) << 3);
        int col = nt * 16 + (l & 15);
        bf16x8 r;
        #pragma unroll
        for (int i = 0; i < 8; ++i)
            r[i] = (short)f2bf(W1[(size_t)(kbase + i) * HID + col]);
        *reinterpret_cast<bf16x8*>(fragW + (size_t)idx * 8) = r;
    } else if (idx < 4096 + HID) {
        int n = idx - 4096;
        bw[n] = make_float2(b1[n], W2[n]);
    }
}

// ---- scan phase 1: per-block sums of deg_in ----
__global__ void k_scan1(const int* __restrict__ deg_in, int* __restrict__ partial) {
    __shared__ int sh[SCAN_BLK];
    int i = blockIdx.x * SCAN_BLK + threadIdx.x;
    int v = (i < NN) ? deg_in[i] : 0;
    sh[threadIdx.x] = v;
    __syncthreads();
    for (int off = SCAN_BLK / 2; off > 0; off >>= 1) {
        if (threadIdx.x < off) sh[threadIdx.x] += sh[threadIdx.x + off];
        __syncthreads();
    }
    if (threadIdx.x == 0) partial[blockIdx.x] = sh[0];
}

// ---- scan phase 2: wave-parallel exclusive scan of 391 partials ----
__global__ void k_scan2(int* __restrict__ partial) {
    int lane = threadIdx.x;
    int carry = 0;
    for (int c = 0; c < NSCAN; c += 64) {
        int idx = c + lane;
        int v = (idx < NSCAN) ? partial[idx] : 0;
        int s = v;
        #pragma unroll
        for (int off = 1; off < 64; off <<= 1) {
            int t = __shfl_up(s, off, 64);
            if (lane >= off) s += t;
        }
        if (idx < NSCAN) partial[idx] = s - v + carry;
        carry += __shfl(s, 63, 64);
    }
}

// ---- scan phase 3: offsets ----
__global__ void k_scan3(const int* __restrict__ deg_in, const int* __restrict__ partial,
                        int* __restrict__ offsets) {
    __shared__ int sh[SCAN_BLK];
    int i = blockIdx.x * SCAN_BLK + threadIdx.x;
    int v = (i < NN) ? deg_in[i] : 0;
    sh[threadIdx.x] = v;
    __syncthreads();
    for (int off = 1; off < SCAN_BLK; off <<= 1) {
        int t = (threadIdx.x >= off) ? sh[threadIdx.x - off] : 0;
        __syncthreads();
        sh[threadIdx.x] += t;
        __syncthreads();
    }
    int ex = sh[threadIdx.x] - v + partial[blockIdx.x];
    if (i < NN) offsets[i] = ex;
    if (i == 0) offsets[NN] = NE;
}

// ---- per-copy cursor bases: cbase[c][v] = offsets[v] + sum_{c'<c} hist_in[c'][v] ----
__global__ void k_cbase(const int* __restrict__ offsets, const int* __restrict__ hist_in,
                        int* __restrict__ cbase) {
    int v = blockIdx.x * blockDim.x + threadIdx.x;
    if (v < NN) {
        int run = offsets[v];
        #pragma unroll
        for (int b = 0; b < NC; ++b) {
            cbase[(size_t)b * NN + v] = run;
            run += hist_in[(size_t)b * NN + v];
        }
    }
}

// ---- CSR fill with LDS cursors: zero global atomics, 1024 thr ----
// block (g = bid&7, c = bid>>3): same chunking as k_hist => per-(chunk,node)
// slot ranges from cbase are exact; cursor slice in LDS (ds_atomic).
__launch_bounds__(1024)
__global__ void k_fill2(const int* __restrict__ src, const int* __restrict__ dst,
                        const int* __restrict__ cbase, int* __restrict__ csr_src) {
    __shared__ int cur[FRNG];
    const int g = blockIdx.x & (FGRP - 1);
    const int c = blockIdx.x >> 3;
    const int lo = g * FRNG;
    const int* cb = cbase + (size_t)c * NN + lo;
    for (int i = threadIdx.x; i < FRNG; i += 1024) cur[i] = cb[i];
    __syncthreads();
    const int e0 = c * CHUNK;
    const int4* d4 = reinterpret_cast<const int4*>(dst + e0);
    for (int k = threadIdx.x; k < CHUNK / 4; k += 1024) {
        int4 v = d4[k];
        int e = e0 + k * 4;
        int i0 = v.x - lo, i1 = v.y - lo, i2 = v.z - lo, i3 = v.w - lo;
        if ((unsigned)i0 < FRNG) { int p = atomicAdd(&cur[i0], 1); csr_src[p] = src[e]; }
        if ((unsigned)i1 < FRNG) { int p = atomicAdd(&cur[i1], 1); csr_src[p] = src[e + 1]; }
        if ((unsigned)i2 < FRNG) { int p = atomicAdd(&cur[i2], 1); csr_src[p] = src[e + 2]; }
        if ((unsigned)i3 < FRNG) { int p = atomicAdd(&cur[i3], 1); csr_src[p] = src[e + 3]; }
    }
}

// ---- gather: aggb[v] = bf16( nrm_in[v] * sum xs[src] ), one wave per row ----
__global__ void k_gather(const unsigned int* __restrict__ xs, const int* __restrict__ offsets,
                         const int* __restrict__ csr_src, const float* __restrict__ nrm_in,
                         unsigned int* __restrict__ aggb) {
    int row = blockIdx.x * 4 + (threadIdx.x >> 6);
    if (row >= NN) return;
    int lane = threadIdx.x & 63;
    int beg = offsets[row], end = offsets[row + 1];
    float a0 = 0.f, a1 = 0.f, b0 = 0.f, b1 = 0.f;
    int j = beg;
    for (; j + 1 < end; j += 2) {
        unsigned int p0 = xs[(size_t)csr_src[j] * 64 + lane];
        unsigned int p1 = xs[(size_t)csr_src[j + 1] * 64 + lane];
        a0 += __uint_as_float(p0 << 16);
        a1 += __uint_as_float(p0 & 0xFFFF0000u);
        b0 += __uint_as_float(p1 << 16);
        b1 += __uint_as_float(p1 & 0xFFFF0000u);
    }
    if (j < end) {
        unsigned int p0 = xs[(size_t)csr_src[j] * 64 + lane];
        a0 += __uint_as_float(p0 << 16);
        a1 += __uint_as_float(p0 & 0xFFFF0000u);
    }
    float ni = nrm_in[row];
    float lo = (a0 + b0) * ni, hi = (a1 + b1) * ni;
    aggb[(size_t)row * 64 + lane] = f2bf(lo) | (f2bf(hi) << 16);
}

// ---- MFMA GEMM (no LDS) + relu + W2-dot + shfl-reduce -> z ----
__launch_bounds__(256)
__global__ void k_gemm(const unsigned short* __restrict__ aggb,
                       const unsigned short* __restrict__ fragW,
                       const float2* __restrict__ bw, const float* __restrict__ nrm_out,
                       float* __restrict__ z) {
    const int l = threadIdx.x & 63;
    const int w = threadIdx.x >> 6;
    const int r0 = blockIdx.x * 64 + w * 16;
    const int n15 = l & 15;
    const int hi = l >> 4;
    const int arow = r0 + n15;

    bf16x8 a[4];
    if (arow < NN) {
        #pragma unroll
        for (int ks = 0; ks < 4; ++ks)
            a[ks] = *reinterpret_cast<const bf16x8*>(aggb + (size_t)arow * INF + ks * 32 + (hi << 3));
    } else {
        #pragma unroll
        for (int ks = 0; ks < 4; ++ks) a[ks] = (bf16x8){0, 0, 0, 0, 0, 0, 0, 0};
    }

    float pacc[4] = {0.f, 0.f, 0.f, 0.f};
    #pragma unroll
    for (int nt = 0; nt < 16; ++nt) {
        f32x4 acc = {0.f, 0.f, 0.f, 0.f};
        #pragma unroll
        for (int ks = 0; ks < 4; ++ks) {
            bf16x8 b = *reinterpret_cast<const bf16x8*>(fragW + (size_t)(((nt * 4 + ks) * 64 + l) << 3));
            acc = __builtin_amdgcn_mfma_f32_16x16x32_bf16(a[ks], b, acc, 0, 0, 0);
        }
        float2 c = bw[nt * 16 + n15];
        #pragma unroll
        for (int g = 0; g < 4; ++g)
            pacc[g] += fmaxf(acc[g] + c.x, 0.f) * c.y;
    }
    #pragma unroll
    for (int off = 1; off < 16; off <<= 1) {
        #pragma unroll
        for (int g = 0; g < 4; ++g) pacc[g] += __shfl_xor(pacc[g], off, 64);
    }
    if (n15 == 0) {
        #pragma unroll
        for (int g = 0; g < 4; ++g) {
            int gr = r0 + (hi << 2) + g;
            if (gr < NN) z[gr] = nrm_out[gr] * pacc[g];
        }
    }
}

// ---- layer-2 gather + sigmoid: 16 lanes per node, shfl reduce ----
__global__ void k_out(const float* __restrict__ z, const int* __restrict__ offsets,
                      const int* __restrict__ csr_src, const float* __restrict__ nrm_in,
                      const float* __restrict__ b2, float* __restrict__ out) {
    int v = blockIdx.x * 16 + (threadIdx.x >> 4);
    if (v >= NN) return;
    int li = threadIdx.x & 15;
    int beg = offsets[v], end = offsets[v + 1];
    float s = 0.f;
    for (int j = beg + li; j < end; j += 16) s += z[csr_src[j]];
    #pragma unroll
    for (int off = 1; off < 16; off <<= 1) s += __shfl_xor(s, off, 64);
    if (li == 0) {
        float val = s * nrm_in[v] + b2[0];
        out[v] = 1.0f / (1.0f + expf(-val));
    }
}

extern "C" void kernel_launch(void* const* d_in, const int* in_sizes, int n_in,
                              void* d_out, int out_size, void* d_ws, size_t ws_size,
                              hipStream_t stream) {
    const float* x   = (const float*)d_in[0];
    const int*   src = (const int*)d_in[1];
    const int*   dst = (const int*)d_in[2];
    const float* W1  = (const float*)d_in[3];
    const float* b1  = (const float*)d_in[4];
    const float* W2  = (const float*)d_in[5];
    const float* b2  = (const float*)d_in[6];
    float* out = (float*)d_out;

    // workspace: hist_out/hist_in/cbase (38.4 MB) alias the xs+aggb span
    // (51.2 MB). Lifetimes: hist_* dead after k_cbase; cbase dead after
    // k_fill2; xs written by k_xconv (after k_cbase), aggb by k_gather
    // (after k_fill2). Total ws ~59.7 MB.
    int*   deg_in  = (int*)d_ws;                     // NN
    int*   offsets = deg_in + NN;                    // NN+1
    int*   partial = offsets + NN + 1;               // NSCAN
    int*   csr_src = partial + NSCAN;                // NE
    float* nrm_out = (float*)(csr_src + NE);         // NN
    float* nrm_in  = nrm_out + NN;                   // NN
    float* z       = nrm_in + NN;                    // NN
    float2* bw     = (float2*)(z + NN);              // HID
    unsigned int* xs   = (unsigned int*)(bw + HID);  // NN*64  (25.6 MB)
    unsigned int* aggb = xs + (size_t)NN * 64;       // NN*64  (25.6 MB)
    unsigned short* fragW = (unsigned short*)(aggb + (size_t)NN * 64);  // 64 KB
    int* hist_out = (int*)xs;                        // NC*NN (12.8 MB)
    int* hist_in  = hist_out + (size_t)NC * NN;      // NC*NN (12.8 MB)
    int* cbase    = hist_in + (size_t)NC * NN;       // NC*NN (12.8 MB, in aggb)

    k_wfrag<<<17, 256, 0, stream>>>(W1, b1, W2, fragW, bw);
    k_hist<<<2 * FGRP * NC, 1024, 0, stream>>>(src, dst, hist_out, hist_in);
    k_norms2<<<(NN + 255) / 256, 256, 0, stream>>>(hist_out, hist_in, nrm_out, nrm_in, deg_in);
    k_scan1<<<NSCAN, SCAN_BLK, 0, stream>>>(deg_in, partial);
    k_scan2<<<1, 64, 0, stream>>>(partial);
    k_scan3<<<NSCAN, SCAN_BLK, 0, stream>>>(deg_in, partial, offsets);
    k_cbase<<<(NN + 255) / 256, 256, 0, stream>>>(offsets, hist_in, cbase);
    k_xconv<<<(NN * 64 + 255) / 256, 256, 0, stream>>>(x, nrm_out, xs);
    k_fill2<<<FGRP * NC, 1024, 0, stream>>>(src, dst, cbase, csr_src);
    k_gather<<<NN / 4, 256, 0, stream>>>(xs, offsets, csr_src, nrm_in, aggb);
    k_gemm<<<(NN + 63) / 64, 256, 0, stream>>>((const unsigned short*)aggb, fragW, bw, nrm_out, z);
    k_out<<<(NN + 15) / 16, 256, 0, stream>>>(z, offsets, csr_src, nrm_in, b2, out);
}

// Round 10
// 204.945 us; speedup vs baseline: 3.0797x; 1.1006x over previous
//
#include <hip/hip_runtime.h>
#include <math.h>

#define NN 100000
#define NE 1600000
#define INF 128
#define HID 256
#define SCAN_BLK 256
#define NSCAN ((NN + SCAN_BLK - 1) / SCAN_BLK)   // 391
#define FGRP 8                    // node-space partitions
#define FRNG (NN / FGRP)          // 12500 nodes per range
#define NC 32                     // edge-stream chunks = histogram copies
#define CHUNK (NE / NC)           // 50000 edges per chunk

typedef short bf16x8 __attribute__((ext_vector_type(8)));
typedef float f32x4 __attribute__((ext_vector_type(4)));

__device__ __forceinline__ unsigned int f2bf(float f) {
    unsigned int u = __float_as_uint(f);
    u = u + 0x7FFFu + ((u >> 16) & 1u);   // RNE
    return u >> 16;
}

// ---- privatized degree histograms, type-split for occupancy ----
__launch_bounds__(1024)
__global__ void k_hist(const int* __restrict__ src, const int* __restrict__ dst,
                       int* __restrict__ hist_out, int* __restrict__ hist_in) {
    __shared__ int h[FRNG];
    const int type = blockIdx.x & 1;
    const int g = (blockIdx.x >> 1) & (FGRP - 1);
    const int c = blockIdx.x >> 4;
    const int lo = g * FRNG;
    for (int i = threadIdx.x; i < FRNG; i += 1024) h[i] = 0;
    __syncthreads();
    const int4* a4 = reinterpret_cast<const int4*>((type ? dst : src) + c * CHUNK);
    for (int k = threadIdx.x; k < CHUNK / 4; k += 1024) {
        int4 v = a4[k];
        int i0 = v.x - lo, i1 = v.y - lo, i2 = v.z - lo, i3 = v.w - lo;
        if ((unsigned)i0 < FRNG) atomicAdd(&h[i0], 1);
        if ((unsigned)i1 < FRNG) atomicAdd(&h[i1], 1);
        if ((unsigned)i2 < FRNG) atomicAdd(&h[i2], 1);
        if ((unsigned)i3 < FRNG) atomicAdd(&h[i3], 1);
    }
    __syncthreads();
    int* out = (type ? hist_in : hist_out) + (size_t)c * NN + lo;
    for (int i = threadIdx.x; i < FRNG; i += 1024) out[i] = h[i];
}

// ---- reduce 32 copies -> norms + deg_in (scan input) ----
__global__ void k_norms2(const int* __restrict__ hist_out, const int* __restrict__ hist_in,
                         float* __restrict__ nrm_out, float* __restrict__ nrm_in,
                         int* __restrict__ deg_in) {
    int v = blockIdx.x * blockDim.x + threadIdx.x;
    if (v < NN) {
        int so = 0, si = 0;
        #pragma unroll
        for (int b = 0; b < NC; ++b) {
            so += hist_out[(size_t)b * NN + v];
            si += hist_in[(size_t)b * NN + v];
        }
        nrm_out[v] = rsqrtf(fmaxf((float)so, 1.0f));
        nrm_in[v]  = rsqrtf(fmaxf((float)si, 1.0f));
        deg_in[v]  = si;
    }
}

// ---- xs = bf16(x * nrm_out[row]), packed 2/uint ----
__global__ void k_xconv(const float* __restrict__ x, const float* __restrict__ nrm_out,
                        unsigned int* __restrict__ xs) {
    int i = blockIdx.x * blockDim.x + threadIdx.x;
    if (i >= NN * (INF / 2)) return;
    int row = i >> 6;
    float n = nrm_out[row];
    float2 v = *reinterpret_cast<const float2*>(x + (size_t)i * 2);
    xs[i] = f2bf(v.x * n) | (f2bf(v.y * n) << 16);
}

// ---- W1 -> fragment-linear bf16 buffer + (b1,W2) pair table ----
__global__ void k_wfrag(const float* __restrict__ W1, const float* __restrict__ b1,
                        const float* __restrict__ W2, unsigned short* __restrict__ fragW,
                        float2* __restrict__ bw) {
    int idx = blockIdx.x * blockDim.x + threadIdx.x;
    if (idx < 4096) {
        int l = idx & 63, ks = (idx >> 6) & 3, nt = idx >> 8;
        int kbase = ks * 32 + ((l >> 4) << 3);
        int col = nt * 16 + (l & 15);
        bf16x8 r;
        #pragma unroll
        for (int i = 0; i < 8; ++i)
            r[i] = (short)f2bf(W1[(size_t)(kbase + i) * HID + col]);
        *reinterpret_cast<bf16x8*>(fragW + (size_t)idx * 8) = r;
    } else if (idx < 4096 + HID) {
        int n = idx - 4096;
        bw[n] = make_float2(b1[n], W2[n]);
    }
}

// ---- scan phase 1 ----
__global__ void k_scan1(const int* __restrict__ deg_in, int* __restrict__ partial) {
    __shared__ int sh[SCAN_BLK];
    int i = blockIdx.x * SCAN_BLK + threadIdx.x;
    int v = (i < NN) ? deg_in[i] : 0;
    sh[threadIdx.x] = v;
    __syncthreads();
    for (int off = SCAN_BLK / 2; off > 0; off >>= 1) {
        if (threadIdx.x < off) sh[threadIdx.x] += sh[threadIdx.x + off];
        __syncthreads();
    }
    if (threadIdx.x == 0) partial[blockIdx.x] = sh[0];
}

// ---- scan phase 2 ----
__global__ void k_scan2(int* __restrict__ partial) {
    int lane = threadIdx.x;
    int carry = 0;
    for (int c = 0; c < NSCAN; c += 64) {
        int idx = c + lane;
        int v = (idx < NSCAN) ? partial[idx] : 0;
        int s = v;
        #pragma unroll
        for (int off = 1; off < 64; off <<= 1) {
            int t = __shfl_up(s, off, 64);
            if (lane >= off) s += t;
        }
        if (idx < NSCAN) partial[idx] = s - v + carry;
        carry += __shfl(s, 63, 64);
    }
}

// ---- scan phase 3 ----
__global__ void k_scan3(const int* __restrict__ deg_in, const int* __restrict__ partial,
                        int* __restrict__ offsets) {
    __shared__ int sh[SCAN_BLK];
    int i = blockIdx.x * SCAN_BLK + threadIdx.x;
    int v = (i < NN) ? deg_in[i] : 0;
    sh[threadIdx.x] = v;
    __syncthreads();
    for (int off = 1; off < SCAN_BLK; off <<= 1) {
        int t = (threadIdx.x >= off) ? sh[threadIdx.x - off] : 0;
        __syncthreads();
        sh[threadIdx.x] += t;
        __syncthreads();
    }
    int ex = sh[threadIdx.x] - v + partial[blockIdx.x];
    if (i < NN) offsets[i] = ex;
    if (i == 0) offsets[NN] = NE;
}

// ---- per-copy cursor bases ----
__global__ void k_cbase(const int* __restrict__ offsets, const int* __restrict__ hist_in,
                        int* __restrict__ cbase) {
    int v = blockIdx.x * blockDim.x + threadIdx.x;
    if (v < NN) {
        int run = offsets[v];
        #pragma unroll
        for (int b = 0; b < NC; ++b) {
            cbase[(size_t)b * NN + v] = run;
            run += hist_in[(size_t)b * NN + v];
        }
    }
}

// ---- CSR fill with LDS cursors ----
__launch_bounds__(1024)
__global__ void k_fill2(const int* __restrict__ src, const int* __restrict__ dst,
                        const int* __restrict__ cbase, int* __restrict__ csr_src) {
    __shared__ int cur[FRNG];
    const int g = blockIdx.x & (FGRP - 1);
    const int c = blockIdx.x >> 3;
    const int lo = g * FRNG;
    const int* cb = cbase + (size_t)c * NN + lo;
    for (int i = threadIdx.x; i < FRNG; i += 1024) cur[i] = cb[i];
    __syncthreads();
    const int e0 = c * CHUNK;
    const int4* d4 = reinterpret_cast<const int4*>(dst + e0);
    for (int k = threadIdx.x; k < CHUNK / 4; k += 1024) {
        int4 v = d4[k];
        int e = e0 + k * 4;
        int i0 = v.x - lo, i1 = v.y - lo, i2 = v.z - lo, i3 = v.w - lo;
        if ((unsigned)i0 < FRNG) { int p = atomicAdd(&cur[i0], 1); csr_src[p] = src[e]; }
        if ((unsigned)i1 < FRNG) { int p = atomicAdd(&cur[i1], 1); csr_src[p] = src[e + 1]; }
        if ((unsigned)i2 < FRNG) { int p = atomicAdd(&cur[i2], 1); csr_src[p] = src[e + 2]; }
        if ((unsigned)i3 < FRNG) { int p = atomicAdd(&cur[i3], 1); csr_src[p] = src[e + 3]; }
    }
}

// ---- gather, 4-way MLP: aggb[v] = bf16( nrm_in[v] * sum xs[src] ) ----
// One wave per row; 4-way unrolled row-load stream + pipelined index
// prefetch -> ~4 outstanding 256B row reads per wave (latency-bound fix).
__global__ void k_gather(const unsigned int* __restrict__ xs, const int* __restrict__ offsets,
                         const int* __restrict__ csr_src, const float* __restrict__ nrm_in,
                         unsigned int* __restrict__ aggb) {
    int row = blockIdx.x * 4 + (threadIdx.x >> 6);
    if (row >= NN) return;
    int lane = threadIdx.x & 63;
    int beg = offsets[row], end = offsets[row + 1];
    float a0 = 0.f, a1 = 0.f, b0 = 0.f, b1 = 0.f;
    float c0 = 0.f, c1 = 0.f, d0 = 0.f, d1 = 0.f;
    int j = beg;
    if (j + 4 <= end) {
        int s0 = csr_src[j], s1 = csr_src[j + 1], s2 = csr_src[j + 2], s3 = csr_src[j + 3];
        while (true) {
            unsigned int p0 = xs[(size_t)s0 * 64 + lane];
            unsigned int p1 = xs[(size_t)s1 * 64 + lane];
            unsigned int p2 = xs[(size_t)s2 * 64 + lane];
            unsigned int p3 = xs[(size_t)s3 * 64 + lane];
            j += 4;
            bool more = (j + 4 <= end);
            if (more) {
                s0 = csr_src[j]; s1 = csr_src[j + 1]; s2 = csr_src[j + 2]; s3 = csr_src[j + 3];
            }
            a0 += __uint_as_float(p0 << 16); a1 += __uint_as_float(p0 & 0xFFFF0000u);
            b0 += __uint_as_float(p1 << 16); b1 += __uint_as_float(p1 & 0xFFFF0000u);
            c0 += __uint_as_float(p2 << 16); c1 += __uint_as_float(p2 & 0xFFFF0000u);
            d0 += __uint_as_float(p3 << 16); d1 += __uint_as_float(p3 & 0xFFFF0000u);
            if (!more) break;
        }
    }
    for (; j < end; ++j) {
        unsigned int p0 = xs[(size_t)csr_src[j] * 64 + lane];
        a0 += __uint_as_float(p0 << 16);
        a1 += __uint_as_float(p0 & 0xFFFF0000u);
    }
    float ni = nrm_in[row];
    float lo = ((a0 + b0) + (c0 + d0)) * ni;
    float hi = ((a1 + b1) + (c1 + d1)) * ni;
    aggb[(size_t)row * 64 + lane] = f2bf(lo) | (f2bf(hi) << 16);
}

// ---- MFMA GEMM (no LDS) + relu + W2-dot + shfl-reduce -> z ----
__launch_bounds__(256)
__global__ void k_gemm(const unsigned short* __restrict__ aggb,
                       const unsigned short* __restrict__ fragW,
                       const float2* __restrict__ bw, const float* __restrict__ nrm_out,
                       float* __restrict__ z) {
    const int l = threadIdx.x & 63;
    const int w = threadIdx.x >> 6;
    const int r0 = blockIdx.x * 64 + w * 16;
    const int n15 = l & 15;
    const int hi = l >> 4;
    const int arow = r0 + n15;

    bf16x8 a[4];
    if (arow < NN) {
        #pragma unroll
        for (int ks = 0; ks < 4; ++ks)
            a[ks] = *reinterpret_cast<const bf16x8*>(aggb + (size_t)arow * INF + ks * 32 + (hi << 3));
    } else {
        #pragma unroll
        for (int ks = 0; ks < 4; ++ks) a[ks] = (bf16x8){0, 0, 0, 0, 0, 0, 0, 0};
    }

    float pacc[4] = {0.f, 0.f, 0.f, 0.f};
    #pragma unroll
    for (int nt = 0; nt < 16; ++nt) {
        f32x4 acc = {0.f, 0.f, 0.f, 0.f};
        #pragma unroll
        for (int ks = 0; ks < 4; ++ks) {
            bf16x8 b = *reinterpret_cast<const bf16x8*>(fragW + (size_t)(((nt * 4 + ks) * 64 + l) << 3));
            acc = __builtin_amdgcn_mfma_f32_16x16x32_bf16(a[ks], b, acc, 0, 0, 0);
        }
        float2 c = bw[nt * 16 + n15];
        #pragma unroll
        for (int g = 0; g < 4; ++g)
            pacc[g] += fmaxf(acc[g] + c.x, 0.f) * c.y;
    }
    #pragma unroll
    for (int off = 1; off < 16; off <<= 1) {
        #pragma unroll
        for (int g = 0; g < 4; ++g) pacc[g] += __shfl_xor(pacc[g], off, 64);
    }
    if (n15 == 0) {
        #pragma unroll
        for (int g = 0; g < 4; ++g) {
            int gr = r0 + (hi << 2) + g;
            if (gr < NN) z[gr] = nrm_out[gr] * pacc[g];
        }
    }
}

// ---- layer-2 gather + sigmoid: 16 lanes per node, shfl reduce ----
__global__ void k_out(const float* __restrict__ z, const int* __restrict__ offsets,
                      const int* __restrict__ csr_src, const float* __restrict__ nrm_in,
                      const float* __restrict__ b2, float* __restrict__ out) {
    int v = blockIdx.x * 16 + (threadIdx.x >> 4);
    if (v >= NN) return;
    int li = threadIdx.x & 15;
    int beg = offsets[v], end = offsets[v + 1];
    float s = 0.f;
    for (int j = beg + li; j < end; j += 16) s += z[csr_src[j]];
    #pragma unroll
    for (int off = 1; off < 16; off <<= 1) s += __shfl_xor(s, off, 64);
    if (li == 0) {
        float val = s * nrm_in[v] + b2[0];
        out[v] = 1.0f / (1.0f + expf(-val));
    }
}

extern "C" void kernel_launch(void* const* d_in, const int* in_sizes, int n_in,
                              void* d_out, int out_size, void* d_ws, size_t ws_size,
                              hipStream_t stream) {
    const float* x   = (const float*)d_in[0];
    const int*   src = (const int*)d_in[1];
    const int*   dst = (const int*)d_in[2];
    const float* W1  = (const float*)d_in[3];
    const float* b1  = (const float*)d_in[4];
    const float* W2  = (const float*)d_in[5];
    const float* b2  = (const float*)d_in[6];
    float* out = (float*)d_out;

    // workspace: hist_out/hist_in/cbase (38.4 MB) alias the xs+aggb span.
    int*   deg_in  = (int*)d_ws;                     // NN
    int*   offsets = deg_in + NN;                    // NN+1
    int*   partial = offsets + NN + 1;               // NSCAN
    int*   csr_src = partial + NSCAN;                // NE
    float* nrm_out = (float*)(csr_src + NE);         // NN
    float* nrm_in  = nrm_out + NN;                   // NN
    float* z       = nrm_in + NN;                    // NN
    float2* bw     = (float2*)(z + NN);              // HID
    unsigned int* xs   = (unsigned int*)(bw + HID);  // NN*64  (25.6 MB)
    unsigned int* aggb = xs + (size_t)NN * 64;       // NN*64  (25.6 MB)
    unsigned short* fragW = (unsigned short*)(aggb + (size_t)NN * 64);  // 64 KB
    int* hist_out = (int*)xs;                        // NC*NN (12.8 MB)
    int* hist_in  = hist_out + (size_t)NC * NN;      // NC*NN (12.8 MB)
    int* cbase    = hist_in + (size_t)NC * NN;       // NC*NN (12.8 MB, in aggb)

    k_wfrag<<<17, 256, 0, stream>>>(W1, b1, W2, fragW, bw);
    k_hist<<<2 * FGRP * NC, 1024, 0, stream>>>(src, dst, hist_out, hist_in);
    k_norms2<<<(NN + 255) / 256, 256, 0, stream>>>(hist_out, hist_in, nrm_out, nrm_in, deg_in);
    k_scan1<<<NSCAN, SCAN_BLK, 0, stream>>>(deg_in, partial);
    k_scan2<<<1, 64, 0, stream>>>(partial);
    k_scan3<<<NSCAN, SCAN_BLK, 0, stream>>>(deg_in, partial, offsets);
    k_cbase<<<(NN + 255) / 256, 256, 0, stream>>>(offsets, hist_in, cbase);
    k_xconv<<<(NN * 64 + 255) / 256, 256, 0, stream>>>(x, nrm_out, xs);
    k_fill2<<<FGRP * NC, 1024, 0, stream>>>(src, dst, cbase, csr_src);
    k_gather<<<NN / 4, 256, 0, stream>>>(xs, offsets, csr_src, nrm_in, aggb);
    k_gemm<<<(NN + 63) / 64, 256, 0, stream>>>((const unsigned short*)aggb, fragW, bw, nrm_out, z);
    k_out<<<(NN + 15) / 16, 256, 0, stream>>>(z, offsets, csr_src, nrm_in, b2, out);
}